// Round 11
// baseline (28.834 us; speedup 1.0000x reference)
//
#include <hip/hip_runtime.h>

// SoftPattern: score = sum_{t=4}^{T-1} prod_{p=0}^{4} sigmoid(e_{doc[t-4+p]} . W[:,p] + b[p])
// W = diags[1]; only pattern positions 0..4 contribute.
//
// Round history: K1 plateau 11.5us (~5.3 TB/s eff) at >=9 waves/CU (R8/R10); ticket
// fusion +12us (R4/R6, cause = __threadfence drain, not atomic); K1+gap = 13.2us (R9).
// R11: 2-kernel structure. K1 (R8 config, 25.75us baseline) also zeroes out[0];
// K2 replaces per-block partials+K3 with ONE device-scope atomicAdd per block
// (489 atomics to one address - negligible; no fence, no ticket).
//
// K1: fused projection+combine+sigmoid -> sig[v][8]
//     block=768: 12 d-groups (25 rows) x 64 lanes; VBLK=128 (float2); grid=391.
// K2: windowed 5-term products, LDS-staged token rows, 1024-thread blocks,
//     one atomicAdd(out) per block.

#define WORD_DIM 300
#define VOCAB    50000
#define PLEN     6
#define DOC_LEN  500000

#define GROUPS   12
#define DCHUNK   25                    // WORD_DIM / GROUPS
#define K1_BLOCK (GROUPS * 64)         // 768
#define VBLK     128                   // 64 lanes x float2

// ------------- K1: sig[v][p] = sigmoid(sum_d E[d][v]*W[d][p] + b[p]) -------------
__global__ __launch_bounds__(K1_BLOCK, 6) void proj_sig_fused(
    const float* __restrict__ emb,     // (WORD_DIM, VOCAB)
    const float* __restrict__ diags,   // (3, WORD_DIM, PLEN)
    const float* __restrict__ bias,    // (3, PLEN)
    float* __restrict__ sig,           // (VOCAB, 8) rows, cols 0..4 valid
    float* __restrict__ out)           // zeroed here for K2's atomics
{
    __shared__ float wl[WORD_DIM * 8];                   // 9.6 KB, 32B rows -> b128 merge
    __shared__ float part[GROUPS - 1][64][11];           // 30.9 KB, odd stride: conflict-free
    const int tid = threadIdx.x;
    if (blockIdx.x == 0 && tid == 0) out[0] = 0.f;       // visible to K2 at kernel boundary
    for (int i = tid; i < WORD_DIM * 5; i += K1_BLOCK) {
        int d = i / 5, p = i % 5;
        wl[d * 8 + p] = diags[WORD_DIM * PLEN + d * PLEN + p];   // diags[1][d][p]
    }
    __syncthreads();

    const int g   = tid >> 6;          // d-group == wave index
    const int u   = tid & 63;          // lane
    const int v2  = blockIdx.x * VBLK + u * 2;
    const bool act = (v2 < VOCAB);     // last block: 40 active lanes
    const int d0  = g * DCHUNK;

    float a[10] = {0.f, 0.f, 0.f, 0.f, 0.f, 0.f, 0.f, 0.f, 0.f, 0.f};
    if (act) {
        const float* __restrict__ col = emb + (size_t)d0 * VOCAB + v2;
        #pragma unroll 5
        for (int dd = 0; dd < DCHUNK; ++dd) {
            float2 x = *reinterpret_cast<const float2*>(&col[(size_t)dd * VOCAB]);
            const float* w = &wl[(d0 + dd) * 8];         // 32B-aligned -> b128+b32 merge
            a[0] += x.x * w[0]; a[1] += x.x * w[1]; a[2] += x.x * w[2];
            a[3] += x.x * w[3]; a[4] += x.x * w[4];
            a[5] += x.y * w[0]; a[6] += x.y * w[1]; a[7] += x.y * w[2];
            a[8] += x.y * w[3]; a[9] += x.y * w[4];
        }
    }
    if (g > 0 && act) {
        #pragma unroll
        for (int k = 0; k < 10; ++k) part[g - 1][u][k] = a[k];
    }
    __syncthreads();
    if (g == 0 && act) {
        #pragma unroll
        for (int k = 0; k < 10; ++k) {
            float s = a[k];
            #pragma unroll
            for (int q = 0; q < GROUPS - 1; ++q) s += part[q][u][k];
            a[k] = s;
        }
        float* r0 = &sig[(size_t)v2 * 8];
        float* r1 = &sig[(size_t)(v2 + 1) * 8];
        #pragma unroll
        for (int p = 0; p < 5; ++p) {
            float b = bias[PLEN + p];                    // bias[1][p]
            r0[p] = 1.f / (1.f + __expf(-(a[p]     + b)));
            r1[p] = 1.f / (1.f + __expf(-(a[5 + p] + b)));
        }
    }
}

// ------------- K2: windowed products + one atomicAdd per block -------------
#define K2_BLOCK 1024
#define K2_TOK   (K2_BLOCK + 4)

__global__ __launch_bounds__(K2_BLOCK) void score_kernel(
    const int* __restrict__ doc,
    const float* __restrict__ sig,     // (VOCAB, 8)
    float* __restrict__ out)
{
    __shared__ float srow[5][K2_TOK];  // plane-per-position: conflict-free stride-1
    const int tid  = threadIdx.x;
    const int base = blockIdx.x * K2_BLOCK + 4;          // first window end t
    for (int i = tid; i < K2_TOK; i += K2_BLOCK) {
        int tok_t = base - 4 + i;
        if (tok_t < DOC_LEN) {
            const float* row = &sig[(size_t)doc[tok_t] * 8];
            float4 r4 = *reinterpret_cast<const float4*>(row);
            srow[0][i] = r4.x; srow[1][i] = r4.y; srow[2][i] = r4.z; srow[3][i] = r4.w;
            srow[4][i] = row[4];
        }
    }
    __syncthreads();

    const int t = base + tid;
    float prod = 0.f;
    if (t < DOC_LEN) {
        prod = srow[0][tid] * srow[1][tid + 1] * srow[2][tid + 2]
             * srow[3][tid + 3] * srow[4][tid + 4];
    }
    #pragma unroll
    for (int off = 32; off > 0; off >>= 1)
        prod += __shfl_down(prod, off, 64);
    __shared__ float wsum[K2_BLOCK / 64];
    const int lane = tid & 63;
    const int wid  = tid >> 6;
    if (lane == 0) wsum[wid] = prod;
    __syncthreads();
    if (tid == 0) {
        float s = 0.f;
        #pragma unroll
        for (int w = 0; w < K2_BLOCK / 64; ++w) s += wsum[w];
        atomicAdd(out, s);             // device-scope; 489 total -> negligible contention
    }
}

extern "C" void kernel_launch(void* const* d_in, const int* in_sizes, int n_in,
                              void* d_out, int out_size, void* d_ws, size_t ws_size,
                              hipStream_t stream) {
    const float* emb   = (const float*)d_in[0];   // (300, 50000)
    const float* diags = (const float*)d_in[1];   // (3, 300, 6)
    const float* bias  = (const float*)d_in[2];   // (3, 6)
    const int*   doc   = (const int*)d_in[3];     // (500000,)
    float* out = (float*)d_out;

    float* ws = (float*)d_ws;
    float* sig = ws;                              // VOCAB*8 floats = 1.6 MB

    const int blocks1 = (VOCAB + VBLK - 1) / VBLK;                   // 391
    const int nwin    = DOC_LEN - 4;                                 // 499996
    const int blocks2 = (nwin + K2_BLOCK - 1) / K2_BLOCK;            // 489

    proj_sig_fused<<<blocks1, K1_BLOCK, 0, stream>>>(emb, diags, bias, sig, out);
    score_kernel<<<blocks2, K2_BLOCK, 0, stream>>>(doc, sig, out);
}

// Round 12
// 24.668 us; speedup vs baseline: 1.1689x; 1.1689x over previous
//
#include <hip/hip_runtime.h>
#include <hip/hip_fp16.h>

// SoftPattern: score = sum_{t=4}^{T-1} prod_{p=0}^{4} sigmoid(e_{doc[t-4+p]} . W[:,p] + b[p])
// W = diags[1]; only pattern positions 0..4 contribute.
//
// Ledger: K1 plateau 11.5us @ >=9 w/CU (R8/R10); ticket fusion +12us (R4/R6);
// single-address atomic +3us (R11); K1+gap=13.2us (R9). K2 modeled gather-bound:
// sig lands in L3 after K1 (XCD L2 writeback at boundary), 500k random row-gathers.
// R12: sig packed fp16 -> 16B row, ONE uint4 gather per token (was float4+float on
// a 32B row): half the gather instrs, 2x line density. Everything else = R8.
//
// K1: fused projection+combine+sigmoid -> sigh[v][8] (fp16, 5 used)
// K2: windowed 5-term products, LDS-staged token rows, 1024-thread blocks
// K3: final deterministic reduction

#define WORD_DIM 300
#define VOCAB    50000
#define PLEN     6
#define DOC_LEN  500000

#define GROUPS   12
#define DCHUNK   25                    // WORD_DIM / GROUPS
#define K1_BLOCK (GROUPS * 64)         // 768
#define VBLK     128                   // 64 lanes x float2

// ------------- K1: sigh[v][p] = fp16(sigmoid(sum_d E[d][v]*W[d][p] + b[p])) -------------
__global__ __launch_bounds__(K1_BLOCK, 6) void proj_sig_fused(
    const float* __restrict__ emb,     // (WORD_DIM, VOCAB)
    const float* __restrict__ diags,   // (3, WORD_DIM, PLEN)
    const float* __restrict__ bias,    // (3, PLEN)
    unsigned short* __restrict__ sigh) // (VOCAB, 8) fp16 rows, cols 0..4 valid
{
    __shared__ float wl[WORD_DIM * 8];                   // 9.6 KB, 32B rows -> b128 merge
    __shared__ float part[GROUPS - 1][64][11];           // 30.9 KB, odd stride: conflict-free
    const int tid = threadIdx.x;
    for (int i = tid; i < WORD_DIM * 5; i += K1_BLOCK) {
        int d = i / 5, p = i % 5;
        wl[d * 8 + p] = diags[WORD_DIM * PLEN + d * PLEN + p];   // diags[1][d][p]
    }
    __syncthreads();

    const int g   = tid >> 6;          // d-group == wave index
    const int u   = tid & 63;          // lane
    const int v2  = blockIdx.x * VBLK + u * 2;
    const bool act = (v2 < VOCAB);     // last block: 40 active lanes
    const int d0  = g * DCHUNK;

    float a[10] = {0.f, 0.f, 0.f, 0.f, 0.f, 0.f, 0.f, 0.f, 0.f, 0.f};
    if (act) {
        const float* __restrict__ col = emb + (size_t)d0 * VOCAB + v2;
        #pragma unroll 5
        for (int dd = 0; dd < DCHUNK; ++dd) {
            float2 x = *reinterpret_cast<const float2*>(&col[(size_t)dd * VOCAB]);
            const float* w = &wl[(d0 + dd) * 8];         // 32B-aligned -> b128+b32 merge
            a[0] += x.x * w[0]; a[1] += x.x * w[1]; a[2] += x.x * w[2];
            a[3] += x.x * w[3]; a[4] += x.x * w[4];
            a[5] += x.y * w[0]; a[6] += x.y * w[1]; a[7] += x.y * w[2];
            a[8] += x.y * w[3]; a[9] += x.y * w[4];
        }
    }
    if (g > 0 && act) {
        #pragma unroll
        for (int k = 0; k < 10; ++k) part[g - 1][u][k] = a[k];
    }
    __syncthreads();
    if (g == 0 && act) {
        #pragma unroll
        for (int k = 0; k < 10; ++k) {
            float s = a[k];
            #pragma unroll
            for (int q = 0; q < GROUPS - 1; ++q) s += part[q][u][k];
            a[k] = s;
        }
        unsigned short h[10];
        #pragma unroll
        for (int j = 0; j < 2; ++j) {
            #pragma unroll
            for (int p = 0; p < 5; ++p) {
                float b = bias[PLEN + p];                // bias[1][p]
                float s = 1.f / (1.f + __expf(-(a[5 * j + p] + b)));
                h[5 * j + p] = __half_as_ushort(__float2half(s));
            }
        }
        // two adjacent 16B rows -> one coalesced 32B region per thread
        uint4 r0, r1;
        r0.x = (unsigned)h[0] | ((unsigned)h[1] << 16);
        r0.y = (unsigned)h[2] | ((unsigned)h[3] << 16);
        r0.z = (unsigned)h[4];
        r0.w = 0u;
        r1.x = (unsigned)h[5] | ((unsigned)h[6] << 16);
        r1.y = (unsigned)h[7] | ((unsigned)h[8] << 16);
        r1.z = (unsigned)h[9];
        r1.w = 0u;
        *reinterpret_cast<uint4*>(&sigh[(size_t)v2 * 8])       = r0;
        *reinterpret_cast<uint4*>(&sigh[(size_t)(v2 + 1) * 8]) = r1;
    }
}

// ------------- K2: windowed products, LDS-staged rows (fp16 gather) -------------
#define K2_BLOCK 1024
#define K2_TOK   (K2_BLOCK + 4)

__global__ __launch_bounds__(K2_BLOCK) void score_kernel(
    const int* __restrict__ doc,
    const unsigned short* __restrict__ sigh,  // (VOCAB, 8) fp16
    float* __restrict__ partials)
{
    __shared__ float srow[5][K2_TOK];  // plane-per-position: conflict-free stride-1
    const int tid  = threadIdx.x;
    const int base = blockIdx.x * K2_BLOCK + 4;          // first window end t
    for (int i = tid; i < K2_TOK; i += K2_BLOCK) {
        int tok_t = base - 4 + i;
        if (tok_t < DOC_LEN) {
            uint4 rw = *reinterpret_cast<const uint4*>(&sigh[(size_t)doc[tok_t] * 8]);
            srow[0][i] = __half2float(__ushort_as_half((unsigned short)(rw.x & 0xffffu)));
            srow[1][i] = __half2float(__ushort_as_half((unsigned short)(rw.x >> 16)));
            srow[2][i] = __half2float(__ushort_as_half((unsigned short)(rw.y & 0xffffu)));
            srow[3][i] = __half2float(__ushort_as_half((unsigned short)(rw.y >> 16)));
            srow[4][i] = __half2float(__ushort_as_half((unsigned short)(rw.z & 0xffffu)));
        }
    }
    __syncthreads();

    const int t = base + tid;
    float prod = 0.f;
    if (t < DOC_LEN) {
        prod = srow[0][tid] * srow[1][tid + 1] * srow[2][tid + 2]
             * srow[3][tid + 3] * srow[4][tid + 4];
    }
    #pragma unroll
    for (int off = 32; off > 0; off >>= 1)
        prod += __shfl_down(prod, off, 64);
    __shared__ float wsum[K2_BLOCK / 64];
    const int lane = tid & 63;
    const int wid  = tid >> 6;
    if (lane == 0) wsum[wid] = prod;
    __syncthreads();
    if (tid == 0) {
        float s = 0.f;
        #pragma unroll
        for (int w = 0; w < K2_BLOCK / 64; ++w) s += wsum[w];
        partials[blockIdx.x] = s;
    }
}

// ------------- K3: final reduction -------------
__global__ __launch_bounds__(512) void reduce_kernel(
    const float* __restrict__ partials, int n, float* __restrict__ out)
{
    float s = 0.f;
    for (int i = threadIdx.x; i < n; i += 512) s += partials[i];
    #pragma unroll
    for (int off = 32; off > 0; off >>= 1)
        s += __shfl_down(s, off, 64);
    __shared__ float wsum[8];
    const int lane = threadIdx.x & 63;
    const int wid  = threadIdx.x >> 6;
    if (lane == 0) wsum[wid] = s;
    __syncthreads();
    if (threadIdx.x == 0) {
        float t = 0.f;
        #pragma unroll
        for (int w = 0; w < 8; ++w) t += wsum[w];
        out[0] = t;
    }
}

extern "C" void kernel_launch(void* const* d_in, const int* in_sizes, int n_in,
                              void* d_out, int out_size, void* d_ws, size_t ws_size,
                              hipStream_t stream) {
    const float* emb   = (const float*)d_in[0];   // (300, 50000)
    const float* diags = (const float*)d_in[1];   // (3, 300, 6)
    const float* bias  = (const float*)d_in[2];   // (3, 6)
    const int*   doc   = (const int*)d_in[3];     // (500000,)
    float* out = (float*)d_out;

    unsigned short* sigh = (unsigned short*)d_ws;            // VOCAB*8 fp16 = 800 KB
    float* bpart = (float*)((char*)d_ws + (size_t)VOCAB * 8 * sizeof(unsigned short));

    const int blocks1 = (VOCAB + VBLK - 1) / VBLK;                   // 391
    const int nwin    = DOC_LEN - 4;                                 // 499996
    const int blocks2 = (nwin + K2_BLOCK - 1) / K2_BLOCK;            // 489

    proj_sig_fused<<<blocks1, K1_BLOCK, 0, stream>>>(emb, diags, bias, sigh);
    score_kernel<<<blocks2, K2_BLOCK, 0, stream>>>(doc, sigh, bpart);
    reduce_kernel<<<1, 512, 0, stream>>>(bpart, blocks2, out);
}